// Round 8
// baseline (242.384 us; speedup 1.0000x reference)
//
#include <hip/hip_runtime.h>

typedef unsigned short u16;
typedef unsigned char  u8;
typedef unsigned int   u32;

typedef short bf16x8 __attribute__((ext_vector_type(8)));
typedef float f32x4  __attribute__((ext_vector_type(4)));
typedef float f32x16 __attribute__((ext_vector_type(16)));

#define DEV __device__ __forceinline__

#if __has_builtin(__builtin_amdgcn_exp2f)
#define EXP2(x) __builtin_amdgcn_exp2f(x)
#else
#define EXP2(x) exp2f(x)
#endif

DEV u16 f2bf(float x) {
  u32 u = __builtin_bit_cast(u32, x);
  u32 r = (u + 0x7fffu + ((u >> 16) & 1u)) >> 16;
  return (u16)r;
}
DEV float bf2f(u16 h) {
  u32 u = ((u32)h) << 16;
  return __builtin_bit_cast(float, u);
}
DEV f32x4 mfma16(bf16x8 a, bf16x8 b, f32x4 c) {
  return __builtin_amdgcn_mfma_f32_16x16x32_bf16(a, b, c, 0, 0, 0);
}
DEV f32x16 mfma32(bf16x8 a, bf16x8 b, f32x16 c) {
  return __builtin_amdgcn_mfma_f32_32x32x16_bf16(a, b, c, 0, 0, 0);
}

#define GLDS(gptr, lptr)                                                  \
  __builtin_amdgcn_global_load_lds(                                       \
      (const __attribute__((address_space(1))) void*)(gptr),              \
      (__attribute__((address_space(3))) void*)(lptr), 16, 0, 0)

// ---------------------------------------------------------------------------
// 1) one-shot split: hidden -> hi/lo, qk_w -> hi/lo, v_w -> hi only
// ---------------------------------------------------------------------------
__global__ __launch_bounds__(256) void split3_kernel(
    const float* __restrict__ hid, const float* __restrict__ wq,
    const float* __restrict__ wv,
    u16* __restrict__ hHi, u16* __restrict__ hLo,
    u16* __restrict__ wqHi, u16* __restrict__ wqLo, u16* __restrict__ wvHi) {
  const int NH = 4194304, NW = 1048576;
  int i = blockIdx.x * 256 + threadIdx.x;
  if (i < NH) {
    float v = hid[i];
    u16 t = f2bf(v);
    hHi[i] = t;
    hLo[i] = f2bf(v - bf2f(t));
  } else if (i < NH + NW) {
    int j = i - NH;
    float v = wq[j];
    u16 t = f2bf(v);
    wqHi[j] = t;
    wqLo[j] = f2bf(v - bf2f(t));
  } else {
    int j = i - NH - NW;
    wvHi[j] = f2bf(wv[j]);
  }
}

// ---------------------------------------------------------------------------
// 2) ca[h][k] = sum_j W[h*64+j][k] * a[j]   (fp64)
// ---------------------------------------------------------------------------
__global__ __launch_bounds__(256) void ca_kernel(
    const float* __restrict__ W, const float* __restrict__ ha, double* __restrict__ ca) {
  int idx = blockIdx.x * 256 + threadIdx.x;  // 16 * 1024
  int h = idx >> 10, k = idx & 1023;
  double s = 0.0;
#pragma unroll 8
  for (int j = 0; j < 64; ++j)
    s += (double)W[(size_t)(h * 64 + j) * 1024 + k] * (double)ha[j];
  ca[idx] = s;
}

// ---------------------------------------------------------------------------
// 3) d[bh][l] = sum_k hidden[row][k] * ca[h][k]   (fp64 acc; exact q-hash sign)
// ---------------------------------------------------------------------------
__global__ __launch_bounds__(256) void d_kernel(
    const float* __restrict__ hid, const double* __restrict__ ca, float* __restrict__ dq) {
  const int row  = blockIdx.x * 4 + (threadIdx.x >> 6);  // 0..4095
  const int lane = threadIdx.x & 63;
  const int b = row >> 11, l = row & 2047;
  double acc[16];
#pragma unroll
  for (int h = 0; h < 16; ++h) acc[h] = 0.0;
  const float* hp = hid + (size_t)row * 1024;
  for (int k = lane; k < 1024; k += 64) {
    const double hv = (double)hp[k];
#pragma unroll
    for (int h = 0; h < 16; ++h) acc[h] += hv * ca[h * 1024 + k];
  }
#pragma unroll
  for (int h = 0; h < 16; ++h) {
    double v = acc[h];
#pragma unroll
    for (int off = 32; off; off >>= 1) v += __shfl_xor(v, off, 64);
    if (lane == 0) dq[(size_t)(b * 16 + h) * 2048 + l] = (float)v;
  }
}

// ---------------------------------------------------------------------------
// 4) dual-output GEMM, grid (64,8), 2 blocks/CU, dbuf prefetch-after-barrier:
//    qk[tok][col] = hidden @ qk_w^T + qk_b  (3-term split)  -> qkB + n2A
//    vt[vcol][tok] = v_w @ hidden^T + v_b                  -> vT (stride 4096)
// ---------------------------------------------------------------------------
__global__ __launch_bounds__(256, 2) void gemm_fused(
    const u16* __restrict__ hHi, const u16* __restrict__ hLo,
    const u16* __restrict__ wqHi, const u16* __restrict__ wqLo,
    const u16* __restrict__ wvHi,
    const float* __restrict__ qk_b, const float* __restrict__ v_b,
    u16* __restrict__ qkB, u16* __restrict__ vT, float* __restrict__ n2A) {
  constexpr int K = 1024;
  // slots (u16): Ah 0, Al 2048, Bh 4096, Bl 8192, Wh 12288; buf stride 16384
  __shared__ u16 S[2][16384];
  const int tid = threadIdx.x, wave = tid >> 6, lane = tid & 63;
  const int quad = lane >> 4, lm = lane & 15;
  const int wr = wave >> 1, wc = wave & 1;
  const int m0 = blockIdx.x * 64, n0 = blockIdx.y * 128;
  const int ch = lane & 3, rA = lane >> 2;

  auto stage = [&](int kt, int buf) {
    const int k0 = kt * 32;
    const int rowA = wave * 16 + rA;
    GLDS(hHi + (size_t)(m0 + rowA) * K + k0 + ch * 8, &S[buf][0 + wave * 512]);
    GLDS(hLo + (size_t)(m0 + rowA) * K + k0 + ch * 8, &S[buf][2048 + wave * 512]);
#pragma unroll
    for (int it = 0; it < 2; ++it) {
      const int rb = wave * 2 + it;
      const int row = rb * 16 + rA;
      GLDS(wqHi + (size_t)(n0 + row) * K + k0 + ch * 8, &S[buf][4096 + rb * 512]);
      GLDS(wqLo + (size_t)(n0 + row) * K + k0 + ch * 8, &S[buf][8192 + rb * 512]);
      GLDS(wvHi + (size_t)(n0 + row) * K + k0 + ch * 8, &S[buf][12288 + rb * 512]);
    }
  };

  f32x4 aq[2][4], av[4][2];
#pragma unroll
  for (int i = 0; i < 2; ++i)
#pragma unroll
    for (int j = 0; j < 4; ++j) aq[i][j] = {0.f, 0.f, 0.f, 0.f};
#pragma unroll
  for (int i = 0; i < 4; ++i)
#pragma unroll
    for (int j = 0; j < 2; ++j) av[i][j] = {0.f, 0.f, 0.f, 0.f};

  stage(0, 0);
  __syncthreads();

  for (int kt = 0; kt < 32; ++kt) {
    const int cur = kt & 1;
    if (kt < 31) stage(kt + 1, cur ^ 1);

    bf16x8 a_h[2], a_l[2], b_h[4], b_l[4], w_h[4];
#pragma unroll
    for (int i = 0; i < 2; ++i) {
      a_h[i] = *(const bf16x8*)&S[cur][(wr * 32 + i * 16 + lm) * 32 + quad * 8];
      a_l[i] = *(const bf16x8*)&S[cur][2048 + (wr * 32 + i * 16 + lm) * 32 + quad * 8];
    }
#pragma unroll
    for (int j = 0; j < 4; ++j) {
      b_h[j] = *(const bf16x8*)&S[cur][4096 + (wc * 64 + j * 16 + lm) * 32 + quad * 8];
      b_l[j] = *(const bf16x8*)&S[cur][8192 + (wc * 64 + j * 16 + lm) * 32 + quad * 8];
      w_h[j] = *(const bf16x8*)&S[cur][12288 + (wc * 64 + j * 16 + lm) * 32 + quad * 8];
    }
#pragma unroll
    for (int i = 0; i < 2; ++i)
#pragma unroll
      for (int j = 0; j < 4; ++j) {
        aq[i][j] = mfma16(a_h[i], b_h[j], aq[i][j]);
        aq[i][j] = mfma16(a_h[i], b_l[j], aq[i][j]);
        aq[i][j] = mfma16(a_l[i], b_h[j], aq[i][j]);
      }
#pragma unroll
    for (int iv = 0; iv < 4; ++iv)
#pragma unroll
      for (int jv = 0; jv < 2; ++jv)
        av[iv][jv] = mfma16(w_h[iv], a_h[jv], av[iv][jv]);

    __syncthreads();
  }

  // qk epilogue + fused per-head n2 (wc-block == one head: cols n0+wc*64..+63)
  const int hidx = blockIdx.y * 2 + wc;
#pragma unroll
  for (int i = 0; i < 2; ++i) {
    float nn[4] = {0.f, 0.f, 0.f, 0.f};
#pragma unroll
    for (int j = 0; j < 4; ++j) {
      const int col = n0 + wc * 64 + j * 16 + lm;
      const float bv = qk_b[col];
#pragma unroll
      for (int r = 0; r < 4; ++r) {
        const int row = m0 + wr * 32 + i * 16 + quad * 4 + r;
        const float val = aq[i][j][r] + bv;
        qkB[(size_t)row * 1024 + col] = f2bf(val);
        nn[r] += val * val;
      }
    }
#pragma unroll
    for (int r = 0; r < 4; ++r)
#pragma unroll
      for (int off = 1; off < 16; off <<= 1) nn[r] += __shfl_xor(nn[r], off, 64);
    if (lm == 0) {
      const int row = m0 + wr * 32 + i * 16 + quad * 4;  // 4 consecutive rows
      const int b = row >> 11, l = row & 2047;
      *(float4*)&n2A[(size_t)(b * 16 + hidx) * 2048 + l] =
          make_float4(nn[0], nn[1], nn[2], nn[3]);
    }
  }
  // v epilogue: vT[vcol][token], token contiguous over lm
#pragma unroll
  for (int iv = 0; iv < 4; ++iv)
#pragma unroll
    for (int r = 0; r < 4; ++r) {
      const int vcol = n0 + wc * 64 + iv * 16 + quad * 4 + r;
      const float bv = v_b[vcol];
#pragma unroll
      for (int jv = 0; jv < 2; ++jv) {
        const int tok = m0 + wr * 32 + jv * 16 + lm;
        vT[(size_t)vcol * 4096 + tok] = f2bf(av[iv][jv][r] + bv);
      }
    }
}

// ---------------------------------------------------------------------------
// 5) hash bits per (b,h)
// ---------------------------------------------------------------------------
__global__ __launch_bounds__(256) void bits_kernel(
    const float* __restrict__ n2A, const float* __restrict__ dq,
    const float* __restrict__ ha, u8* __restrict__ hqA, u8* __restrict__ hkA) {
  const int bh = blockIdx.x;
  const int tid = threadIdx.x;
  const int wave = tid >> 6, lane = tid & 63;
  __shared__ float red[4];
  const float* n2p = n2A + (size_t)bh * 2048;
  float4 v0 = ((const float4*)n2p)[tid];
  float4 v1 = ((const float4*)n2p)[tid + 256];
  float lmax = fmaxf(fmaxf(fmaxf(v0.x, v0.y), fmaxf(v0.z, v0.w)),
                     fmaxf(fmaxf(v1.x, v1.y), fmaxf(v1.z, v1.w)));
#pragma unroll
  for (int off = 1; off < 64; off <<= 1) lmax = fmaxf(lmax, __shfl_xor(lmax, off, 64));
  if (lane == 0) red[wave] = lmax;
  __syncthreads();
  const float maxn2 = fmaxf(fmaxf(red[0], red[1]), fmaxf(red[2], red[3]));
  const float s = 0.75f / fmaxf(sqrtf(maxn2), 1e-12f);
  const float a64 = ha[64], a65 = ha[65];
#pragma unroll
  for (int it = 0; it < 8; ++it) {
    const int l = it * 256 + tid;
    const float dv = dq[(size_t)bh * 2048 + l];
    const float n2 = n2p[l];
    const float nk2 = s * s * n2;
    const float hkdot = s * dv + (0.5f - nk2) * a64 + (0.5f - nk2 * nk2) * a65;
    hqA[(size_t)bh * 2048 + l] = (dv >= 0.f) ? 1 : 0;
    hkA[(size_t)bh * 2048 + l] = (hkdot >= 0.f) ? 1 : 0;
  }
}

// ---------------------------------------------------------------------------
// 6) flash attention v5: 32x32x16 MFMA (2x FLOP/LDS-byte), 128 q/block,
//    32 q/wave, Q in registers, fixed-C softmax, dbuf GLDS staging w/ XOR
//    swizzle, 1 barrier/iter, l via MFMA-with-ones. grid (16,32).
//    C/D map (m74/m101): col=lane&31, row=(reg&3)+8*(reg>>2)+4*(lane>>5).
// ---------------------------------------------------------------------------
__global__ __launch_bounds__(256, 2) void attn_kernel(
    const u16* __restrict__ qkb, const u16* __restrict__ vT,
    const u8* __restrict__ hqA, const u8* __restrict__ hkA, float* __restrict__ out) {
  __shared__ u16 Ks[2][4096];   // [buf][key(64) x dim(64)], 16B-chunk XOR swizzle
  __shared__ u16 Vs[2][4096];   // [buf][dim(64) x key(64)], same swizzle
  __shared__ u16 Ps[4][2048];   // [wave][qrow(32) x key(64)], same swizzle

  const int qt = blockIdx.x;    // 0..15 (128 queries each)
  const int bh = blockIdx.y;    // 0..31
  const int b = bh >> 4, h = bh & 15;
  const int tid = threadIdx.x, wave = tid >> 6, lane = tid & 63;
  const int l32 = lane & 31, half = lane >> 5;
  const int r8 = lane >> 3, ch = lane & 7;
  const int q0 = qt * 128;

  const u16* qbase = qkb + (size_t)b * 2048 * 1024 + h * 64;
  const u16* vtb = vT + (size_t)h * 64 * 4096 + b * 2048;  // row stride 4096
  const u8* hkp = hkA + (size_t)bh * 2048;

  // Q A-frags (loop-invariant, in registers): A[m=l32][k=half*8+j], 4 k-tiles
  bf16x8 aQ[4];
#pragma unroll
  for (int kt = 0; kt < 4; ++kt)
    aQ[kt] = *(const bf16x8*)(qbase +
        (size_t)(q0 + wave * 32 + l32) * 1024 + kt * 16 + half * 8);
  // hq bits for this lane's 16 C-rows
  u8 hqb[16];
  {
    const u8* hqp = hqA + (size_t)bh * 2048 + q0 + wave * 32;
#pragma unroll
    for (int reg = 0; reg < 16; ++reg)
      hqb[reg] = hqp[(reg & 3) + 8 * (reg >> 2) + 4 * half];
  }

  const int srow = wave * 16;  // this wave's 16-row staging slab
  auto stage = [&](int kt, int buf) {
#pragma unroll
    for (int i = 0; i < 2; ++i) {
      const int row = srow + i * 8 + r8;  // key row for K / dim row for V
      const int sw = (ch ^ (row & 7)) * 8;
      GLDS(qbase + (size_t)(kt * 64 + row) * 1024 + sw, &Ks[buf][(srow + i * 8) * 64]);
      GLDS(vtb + (size_t)row * 4096 + kt * 64 + sw, &Vs[buf][(srow + i * 8) * 64]);
    }
  };

  stage(0, 0);

  f32x16 acc_o[2], accL;
#pragma unroll
  for (int e = 0; e < 16; ++e) { acc_o[0][e] = 0.f; acc_o[1][e] = 0.f; accL[e] = 0.f; }
  const bf16x8 ones = {0x3F80, 0x3F80, 0x3F80, 0x3F80, 0x3F80, 0x3F80, 0x3F80, 0x3F80};
  const float SCL = 0.18033688f;        // 0.125 * log2(e)
  const float M0 = -4.3280854f;         // -C*log2(e), C = 3
  const float M1 = -1.4430768e4f;       // -(1e4 + C)*log2(e)  -> exp2 underflows to 0

  __syncthreads();  // tile 0 staged (barrier drains vmcnt)

  for (int ktile = 0; ktile < 32; ++ktile) {
    const int cur = ktile & 1;
    if (ktile < 31) stage(ktile + 1, cur ^ 1);

    u8 hkv[2];
#pragma unroll
    for (int nb = 0; nb < 2; ++nb) hkv[nb] = hkp[ktile * 64 + nb * 32 + l32];

    // S = Q K^T : 2 key-blocks x 4 k-tiles of 32x32x16
    f32x16 cs[2];
#pragma unroll
    for (int e = 0; e < 16; ++e) { cs[0][e] = 0.f; cs[1][e] = 0.f; }
#pragma unroll
    for (int kt = 0; kt < 4; ++kt)
#pragma unroll
      for (int nb = 0; nb < 2; ++nb) {
        const int key = nb * 32 + l32;
        bf16x8 bK = *(const bf16x8*)&Ks[cur][key * 64 + (((kt * 2 + half) ^ (key & 7)) * 8)];
        cs[nb] = mfma32(aQ[kt], bK, cs[nb]);
      }

    // p = 2^(s*SCL + msel); write bf16 (truncation) into swizzled Ps
#pragma unroll
    for (int nb = 0; nb < 2; ++nb)
#pragma unroll
      for (int reg = 0; reg < 16; ++reg) {
        const float msel = (hqb[reg] == hkv[nb]) ? M0 : M1;
        const float p = EXP2(__builtin_fmaf(cs[nb][reg], SCL, msel));
        const int prow = (reg & 3) + 8 * (reg >> 2) + 4 * half;
        const int key = nb * 32 + l32;
        const int pos = (key >> 3) ^ (prow & 7);
        union { float f; u16 hw[2]; } u;
        u.f = p;
        Ps[wave][prow * 64 + pos * 8 + (key & 7)] = u.hw[1];
      }

    // P A-frags (same-wave round trip; lgkm ordering, no barrier)
    bf16x8 aP[4];
#pragma unroll
    for (int kt = 0; kt < 4; ++kt) {
      aP[kt] = *(const bf16x8*)&Ps[wave][l32 * 64 + (((kt * 2 + half) ^ (l32 & 7)) * 8)];
      accL = mfma32(aP[kt], ones, accL);   // row sums ride the matrix pipe
    }
    // O += P V
#pragma unroll
    for (int kt = 0; kt < 4; ++kt)
#pragma unroll
      for (int nblk = 0; nblk < 2; ++nblk) {
        const int d = nblk * 32 + l32;
        bf16x8 bV = *(const bf16x8*)&Vs[cur][d * 64 + (((kt * 2 + half) ^ (d & 7)) * 8)];
        acc_o[nblk] = mfma32(aP[kt], bV, acc_o[nblk]);
      }

    __syncthreads();  // prev-tile reads done + next-tile staging drained
  }

#pragma unroll
  for (int reg = 0; reg < 16; ++reg) {
    const float inv = 1.0f / accL[reg];
    const int qrow = q0 + wave * 32 + (reg & 3) + 8 * (reg >> 2) + 4 * half;
    float* op = out + (size_t)(b * 2048 + qrow) * 1024 + h * 64;
#pragma unroll
    for (int nblk = 0; nblk < 2; ++nblk)
      op[nblk * 32 + l32] = acc_o[nblk][reg] * inv;
  }
}

// ---------------------------------------------------------------------------
extern "C" void kernel_launch(void* const* d_in, const int* in_sizes, int n_in,
                              void* d_out, int out_size, void* d_ws, size_t ws_size,
                              hipStream_t stream) {
  const float* hidden = (const float*)d_in[0];
  const float* qk_w   = (const float*)d_in[1];
  const float* qk_b   = (const float*)d_in[2];
  const float* v_w    = (const float*)d_in[3];
  const float* v_b    = (const float*)d_in[4];
  const float* hash_a = (const float*)d_in[5];
  float* out = (float*)d_out;

  char* base = (char*)d_ws;
  size_t off = 0;
  auto take = [&](size_t bytes) -> char* {
    char* r = base + off;
    off += (bytes + 255) & ~(size_t)255;
    return r;
  };
  const size_t NH = 4194304;  // B*L*D
  const size_t NW = 1048576;  // D*D
  u16* hHi  = (u16*)take(NH * 2);
  u16* hLo  = (u16*)take(NH * 2);
  u16* wqHi = (u16*)take(NW * 2);
  u16* wqLo = (u16*)take(NW * 2);
  u16* wvHi = (u16*)take(NW * 2);
  u16* qkB  = (u16*)take(NH * 2);
  u16* vT   = (u16*)take(NH * 2);
  double* ca = (double*)take(16 * 1024 * 8);
  float* dq  = (float*)take(65536 * 4);
  float* n2A = (float*)take(65536 * 4);
  u8* hqA = (u8*)take(65536);
  u8* hkA = (u8*)take(65536);

  hipLaunchKernelGGL(split3_kernel, dim3((NH + 2 * NW) / 256), dim3(256), 0, stream,
                     hidden, qk_w, v_w, hHi, hLo, wqHi, wqLo, wvHi);
  hipLaunchKernelGGL(ca_kernel, dim3(64), dim3(256), 0, stream, qk_w, hash_a, ca);
  hipLaunchKernelGGL(d_kernel, dim3(1024), dim3(256), 0, stream, hidden, ca, dq);
  hipLaunchKernelGGL(gemm_fused, dim3(64, 8), dim3(256), 0, stream,
                     hHi, hLo, wqHi, wqLo, wvHi, qk_b, v_b, qkB, vT, n2A);
  hipLaunchKernelGGL(bits_kernel, dim3(32), dim3(256), 0, stream, n2A, dq, hash_a, hqA, hkA);
  hipLaunchKernelGGL(attn_kernel, dim3(16, 32), dim3(256), 0, stream, qkB, vT, hqA, hkA, out);
}

// Round 9
// 234.382 us; speedup vs baseline: 1.0341x; 1.0341x over previous
//
#include <hip/hip_runtime.h>

typedef unsigned short u16;
typedef unsigned char  u8;
typedef unsigned int   u32;

typedef short bf16x8 __attribute__((ext_vector_type(8)));
typedef float f32x4  __attribute__((ext_vector_type(4)));

#define DEV __device__ __forceinline__

#if __has_builtin(__builtin_amdgcn_exp2f)
#define EXP2(x) __builtin_amdgcn_exp2f(x)
#else
#define EXP2(x) exp2f(x)
#endif

DEV u16 f2bf(float x) {
  u32 u = __builtin_bit_cast(u32, x);
  u32 r = (u + 0x7fffu + ((u >> 16) & 1u)) >> 16;
  return (u16)r;
}
DEV float bf2f(u16 h) {
  u32 u = ((u32)h) << 16;
  return __builtin_bit_cast(float, u);
}
DEV f32x4 mfma16(bf16x8 a, bf16x8 b, f32x4 c) {
  return __builtin_amdgcn_mfma_f32_16x16x32_bf16(a, b, c, 0, 0, 0);
}

#define GLDS(gptr, lptr)                                                  \
  __builtin_amdgcn_global_load_lds(                                       \
      (const __attribute__((address_space(1))) void*)(gptr),              \
      (__attribute__((address_space(3))) void*)(lptr), 16, 0, 0)

// ---------------------------------------------------------------------------
// 1) merged preprocessing (raw inputs only):
//    blocks [0, 24576): split hidden->hi/lo, qk_w->hi/lo, v_w->hi
//    blocks [24576, 24640): ca[h][k] = sum_j qk_w[h*64+j][k]*a[j]  (fp64)
// ---------------------------------------------------------------------------
__global__ __launch_bounds__(256) void prep_kernel(
    const float* __restrict__ hid, const float* __restrict__ wq,
    const float* __restrict__ wv, const float* __restrict__ ha,
    u16* __restrict__ hHi, u16* __restrict__ hLo,
    u16* __restrict__ wqHi, u16* __restrict__ wqLo, u16* __restrict__ wvHi,
    double* __restrict__ ca) {
  const int NH = 4194304, NW = 1048576;
  int i = blockIdx.x * 256 + threadIdx.x;
  if (i < NH) {
    float v = hid[i];
    u16 t = f2bf(v);
    hHi[i] = t;
    hLo[i] = f2bf(v - bf2f(t));
  } else if (i < NH + NW) {
    int j = i - NH;
    float v = wq[j];
    u16 t = f2bf(v);
    wqHi[j] = t;
    wqLo[j] = f2bf(v - bf2f(t));
  } else if (i < NH + 2 * NW) {
    int j = i - NH - NW;
    wvHi[j] = f2bf(wv[j]);
  } else {
    int idx = i - NH - 2 * NW;  // 0 .. 16383
    int h = idx >> 10, k = idx & 1023;
    double s = 0.0;
#pragma unroll 8
    for (int j = 0; j < 64; ++j)
      s += (double)wq[(size_t)(h * 64 + j) * 1024 + k] * (double)ha[j];
    ca[idx] = s;
  }
}

// ---------------------------------------------------------------------------
// 3) d[bh][l] = sum_k hidden[row][k] * ca[h][k]   (fp64 acc; exact q-hash sign)
// ---------------------------------------------------------------------------
__global__ __launch_bounds__(256) void d_kernel(
    const float* __restrict__ hid, const double* __restrict__ ca, float* __restrict__ dq) {
  const int row  = blockIdx.x * 4 + (threadIdx.x >> 6);  // 0..4095
  const int lane = threadIdx.x & 63;
  const int b = row >> 11, l = row & 2047;
  double acc[16];
#pragma unroll
  for (int h = 0; h < 16; ++h) acc[h] = 0.0;
  const float* hp = hid + (size_t)row * 1024;
  for (int k = lane; k < 1024; k += 64) {
    const double hv = (double)hp[k];
#pragma unroll
    for (int h = 0; h < 16; ++h) acc[h] += hv * ca[h * 1024 + k];
  }
#pragma unroll
  for (int h = 0; h < 16; ++h) {
    double v = acc[h];
#pragma unroll
    for (int off = 32; off; off >>= 1) v += __shfl_xor(v, off, 64);
    if (lane == 0) dq[(size_t)(b * 16 + h) * 2048 + l] = (float)v;
  }
}

// ---------------------------------------------------------------------------
// 4) dual-output GEMM, grid (64,8), 2 blocks/CU, dbuf prefetch-after-barrier:
//    qk[tok][col] = hidden @ qk_w^T + qk_b  (3-term split)  -> qkB + n2A
//    vt[vcol][tok] = v_w @ hidden^T + v_b                  -> vT (stride 4096)
// ---------------------------------------------------------------------------
__global__ __launch_bounds__(256, 2) void gemm_fused(
    const u16* __restrict__ hHi, const u16* __restrict__ hLo,
    const u16* __restrict__ wqHi, const u16* __restrict__ wqLo,
    const u16* __restrict__ wvHi,
    const float* __restrict__ qk_b, const float* __restrict__ v_b,
    u16* __restrict__ qkB, u16* __restrict__ vT, float* __restrict__ n2A) {
  constexpr int K = 1024;
  // slots (u16): Ah 0, Al 2048, Bh 4096, Bl 8192, Wh 12288; buf stride 16384
  __shared__ u16 S[2][16384];
  const int tid = threadIdx.x, wave = tid >> 6, lane = tid & 63;
  const int quad = lane >> 4, lm = lane & 15;
  const int wr = wave >> 1, wc = wave & 1;
  const int m0 = blockIdx.x * 64, n0 = blockIdx.y * 128;
  const int ch = lane & 3, rA = lane >> 2;

  auto stage = [&](int kt, int buf) {
    const int k0 = kt * 32;
    const int rowA = wave * 16 + rA;
    GLDS(hHi + (size_t)(m0 + rowA) * K + k0 + ch * 8, &S[buf][0 + wave * 512]);
    GLDS(hLo + (size_t)(m0 + rowA) * K + k0 + ch * 8, &S[buf][2048 + wave * 512]);
#pragma unroll
    for (int it = 0; it < 2; ++it) {
      const int rb = wave * 2 + it;
      const int row = rb * 16 + rA;
      GLDS(wqHi + (size_t)(n0 + row) * K + k0 + ch * 8, &S[buf][4096 + rb * 512]);
      GLDS(wqLo + (size_t)(n0 + row) * K + k0 + ch * 8, &S[buf][8192 + rb * 512]);
      GLDS(wvHi + (size_t)(n0 + row) * K + k0 + ch * 8, &S[buf][12288 + rb * 512]);
    }
  };

  f32x4 aq[2][4], av[4][2];
#pragma unroll
  for (int i = 0; i < 2; ++i)
#pragma unroll
    for (int j = 0; j < 4; ++j) aq[i][j] = {0.f, 0.f, 0.f, 0.f};
#pragma unroll
  for (int i = 0; i < 4; ++i)
#pragma unroll
    for (int j = 0; j < 2; ++j) av[i][j] = {0.f, 0.f, 0.f, 0.f};

  stage(0, 0);
  __syncthreads();

  for (int kt = 0; kt < 32; ++kt) {
    const int cur = kt & 1;
    if (kt < 31) stage(kt + 1, cur ^ 1);

    bf16x8 a_h[2], a_l[2], b_h[4], b_l[4], w_h[4];
#pragma unroll
    for (int i = 0; i < 2; ++i) {
      a_h[i] = *(const bf16x8*)&S[cur][(wr * 32 + i * 16 + lm) * 32 + quad * 8];
      a_l[i] = *(const bf16x8*)&S[cur][2048 + (wr * 32 + i * 16 + lm) * 32 + quad * 8];
    }
#pragma unroll
    for (int j = 0; j < 4; ++j) {
      b_h[j] = *(const bf16x8*)&S[cur][4096 + (wc * 64 + j * 16 + lm) * 32 + quad * 8];
      b_l[j] = *(const bf16x8*)&S[cur][8192 + (wc * 64 + j * 16 + lm) * 32 + quad * 8];
      w_h[j] = *(const bf16x8*)&S[cur][12288 + (wc * 64 + j * 16 + lm) * 32 + quad * 8];
    }
#pragma unroll
    for (int i = 0; i < 2; ++i)
#pragma unroll
      for (int j = 0; j < 4; ++j) {
        aq[i][j] = mfma16(a_h[i], b_h[j], aq[i][j]);
        aq[i][j] = mfma16(a_h[i], b_l[j], aq[i][j]);
        aq[i][j] = mfma16(a_l[i], b_h[j], aq[i][j]);
      }
#pragma unroll
    for (int iv = 0; iv < 4; ++iv)
#pragma unroll
      for (int jv = 0; jv < 2; ++jv)
        av[iv][jv] = mfma16(w_h[iv], a_h[jv], av[iv][jv]);

    __syncthreads();
  }

  // qk epilogue + fused per-head n2 (wc-block == one head: cols n0+wc*64..+63)
  const int hidx = blockIdx.y * 2 + wc;
#pragma unroll
  for (int i = 0; i < 2; ++i) {
    float nn[4] = {0.f, 0.f, 0.f, 0.f};
#pragma unroll
    for (int j = 0; j < 4; ++j) {
      const int col = n0 + wc * 64 + j * 16 + lm;
      const float bv = qk_b[col];
#pragma unroll
      for (int r = 0; r < 4; ++r) {
        const int row = m0 + wr * 32 + i * 16 + quad * 4 + r;
        const float val = aq[i][j][r] + bv;
        qkB[(size_t)row * 1024 + col] = f2bf(val);
        nn[r] += val * val;
      }
    }
#pragma unroll
    for (int r = 0; r < 4; ++r)
#pragma unroll
      for (int off = 1; off < 16; off <<= 1) nn[r] += __shfl_xor(nn[r], off, 64);
    if (lm == 0) {
      const int row = m0 + wr * 32 + i * 16 + quad * 4;  // 4 consecutive rows
      const int b = row >> 11, l = row & 2047;
      *(float4*)&n2A[(size_t)(b * 16 + hidx) * 2048 + l] =
          make_float4(nn[0], nn[1], nn[2], nn[3]);
    }
  }
  // v epilogue: vT[vcol][token], token contiguous over lm
#pragma unroll
  for (int iv = 0; iv < 4; ++iv)
#pragma unroll
    for (int r = 0; r < 4; ++r) {
      const int vcol = n0 + wc * 64 + iv * 16 + quad * 4 + r;
      const float bv = v_b[vcol];
#pragma unroll
      for (int jv = 0; jv < 2; ++jv) {
        const int tok = m0 + wr * 32 + jv * 16 + lm;
        vT[(size_t)vcol * 4096 + tok] = f2bf(av[iv][jv][r] + bv);
      }
    }
}

// ---------------------------------------------------------------------------
// 5) hash bits per (b,h)
// ---------------------------------------------------------------------------
__global__ __launch_bounds__(256) void bits_kernel(
    const float* __restrict__ n2A, const float* __restrict__ dq,
    const float* __restrict__ ha, u8* __restrict__ hqA, u8* __restrict__ hkA) {
  const int bh = blockIdx.x;
  const int tid = threadIdx.x;
  const int wave = tid >> 6, lane = tid & 63;
  __shared__ float red[4];
  const float* n2p = n2A + (size_t)bh * 2048;
  float4 v0 = ((const float4*)n2p)[tid];
  float4 v1 = ((const float4*)n2p)[tid + 256];
  float lmax = fmaxf(fmaxf(fmaxf(v0.x, v0.y), fmaxf(v0.z, v0.w)),
                     fmaxf(fmaxf(v1.x, v1.y), fmaxf(v1.z, v1.w)));
#pragma unroll
  for (int off = 1; off < 64; off <<= 1) lmax = fmaxf(lmax, __shfl_xor(lmax, off, 64));
  if (lane == 0) red[wave] = lmax;
  __syncthreads();
  const float maxn2 = fmaxf(fmaxf(red[0], red[1]), fmaxf(red[2], red[3]));
  const float s = 0.75f / fmaxf(sqrtf(maxn2), 1e-12f);
  const float a64 = ha[64], a65 = ha[65];
#pragma unroll
  for (int it = 0; it < 8; ++it) {
    const int l = it * 256 + tid;
    const float dv = dq[(size_t)bh * 2048 + l];
    const float n2 = n2p[l];
    const float nk2 = s * s * n2;
    const float hkdot = s * dv + (0.5f - nk2) * a64 + (0.5f - nk2 * nk2) * a65;
    hqA[(size_t)bh * 2048 + l] = (dv >= 0.f) ? 1 : 0;
    hkA[(size_t)bh * 2048 + l] = (hkdot >= 0.f) ? 1 : 0;
  }
}

// ---------------------------------------------------------------------------
// 6) flash attention v4 (reverted from v5 regression): 64 q/block (16 q/wave),
//    grid (32,32) = 4 blocks/CU (LDS 40 KB), fixed-C softmax, dbuf GLDS
//    staging w/ XOR swizzle, 1 barrier/iter, l via MFMA-with-ones.
// ---------------------------------------------------------------------------
__global__ __launch_bounds__(256, 4) void attn_kernel(
    const u16* __restrict__ qkb, const u16* __restrict__ vT,
    const u8* __restrict__ hqA, const u8* __restrict__ hkA, float* __restrict__ out) {
  __shared__ u16 Ks[2][4096];   // [buf][key(64) x dim(64)], 16B-chunk XOR swizzle
  __shared__ u16 Vs[2][4096];   // [buf][dim(64) x key(64)], same swizzle
  __shared__ u16 Ps[4][1024];   // [wave][qrow(16) x key(64)], same swizzle

  const int qt = blockIdx.x;    // 0..31 (64 queries each)
  const int bh = blockIdx.y;    // 0..31
  const int b = bh >> 4, h = bh & 15;
  const int tid = threadIdx.x, wave = tid >> 6, lane = tid & 63;
  const int quad = lane >> 4, lm = lane & 15;
  const int lx = lm & 7;
  const int r8 = lane >> 3, ch = lane & 7;
  const int q0 = qt * 64;

  const u16* qbase = qkb + (size_t)b * 2048 * 1024 + h * 64;
  const u16* vtb = vT + (size_t)h * 64 * 4096 + b * 2048;  // row stride 4096
  const u8* hkp = hkA + (size_t)bh * 2048;

  // Q A-frags straight from global (raw; 1/sqrt(DH) folded into exp2 arg)
  bf16x8 aQ[2];
#pragma unroll
  for (int c = 0; c < 2; ++c)
    aQ[c] = *(const bf16x8*)(qbase +
        (size_t)(q0 + wave * 16 + lm) * 1024 + c * 32 + quad * 8);
  u8 hqb[4];
  {
    const u8* hqp = hqA + (size_t)bh * 2048 + q0 + wave * 16;
#pragma unroll
    for (int r = 0; r < 4; ++r) hqb[r] = hqp[quad * 4 + r];
  }

  const int srow = wave * 16;  // this wave's 16-row staging slab
  auto stage = [&](int kt, int buf) {
#pragma unroll
    for (int i = 0; i < 2; ++i) {
      const int row = srow + i * 8 + r8;  // key row for K / dim row for V
      const int sw = (ch ^ (row & 7)) * 8;
      GLDS(qbase + (size_t)(kt * 64 + row) * 1024 + sw, &Ks[buf][(srow + i * 8) * 64]);
      GLDS(vtb + (size_t)row * 4096 + kt * 64 + sw, &Vs[buf][(srow + i * 8) * 64]);
    }
  };

  stage(0, 0);

  f32x4 acc_o[4], accL;
  accL = {0.f, 0.f, 0.f, 0.f};
#pragma unroll
  for (int j = 0; j < 4; ++j) acc_o[j] = {0.f, 0.f, 0.f, 0.f};
  const bf16x8 ones = {0x3F80, 0x3F80, 0x3F80, 0x3F80, 0x3F80, 0x3F80, 0x3F80, 0x3F80};
  const float SCL = 0.18033688f;        // 0.125 * log2(e)
  const float M0 = -4.3280854f;         // -C*log2(e), C = 3
  const float M1 = -1.4430768e4f;       // -(1e4 + C)*log2(e)  -> exp2 underflows to 0

  __syncthreads();  // tile 0 staged (barrier drains vmcnt)

  for (int kt = 0; kt < 32; ++kt) {
    const int cur = kt & 1;
    if (kt < 31) stage(kt + 1, cur ^ 1);

    u8 hkv[4];
#pragma unroll
    for (int nb = 0; nb < 4; ++nb) hkv[nb] = hkp[kt * 64 + nb * 16 + lm];

    // S = Q K^T (raw dot products; scaling folded into exp)
    f32x4 cs[4];
#pragma unroll
    for (int nb = 0; nb < 4; ++nb) cs[nb] = {0.f, 0.f, 0.f, 0.f};
#pragma unroll
    for (int c = 0; c < 2; ++c)
#pragma unroll
      for (int nb = 0; nb < 4; ++nb) {
        bf16x8 bK = *(const bf16x8*)&Ks[cur][(nb * 16 + lm) * 64 + (((c * 4 + quad) ^ lx) * 8)];
        cs[nb] = mfma16(aQ[c], bK, cs[nb]);
      }

    // p = 2^(s*SCL + msel); write bf16 (truncation) into swizzled Ps
#pragma unroll
    for (int nb = 0; nb < 4; ++nb)
#pragma unroll
      for (int r = 0; r < 4; ++r) {
        const float msel = (hqb[r] == hkv[nb]) ? M0 : M1;
        const float p = EXP2(__builtin_fmaf(cs[nb][r], SCL, msel));
        const int prow = quad * 4 + r;
        const int pc = (nb * 2 + (lm >> 3)) ^ (prow & 7);
        union { float f; u16 hw[2]; } u;
        u.f = p;
        Ps[wave][prow * 64 + pc * 8 + lx] = u.hw[1];
      }

    // P frags (same-wave round trip; lgkm ordering, no barrier) + l via ones-MFMA
    bf16x8 aP[2];
#pragma unroll
    for (int c = 0; c < 2; ++c) {
      aP[c] = *(const bf16x8*)&Ps[wave][lm * 64 + (((c * 4 + quad) ^ lx) * 8)];
      accL = mfma16(aP[c], ones, accL);
    }
    // O += P V
#pragma unroll
    for (int c = 0; c < 2; ++c)
#pragma unroll
      for (int j = 0; j < 4; ++j) {
        bf16x8 bV = *(const bf16x8*)&Vs[cur][(j * 16 + lm) * 64 + (((c * 4 + quad) ^ lx) * 8)];
        acc_o[j] = mfma16(aP[c], bV, acc_o[j]);
      }

    __syncthreads();  // prev-tile reads done + next-tile staging drained
  }

#pragma unroll
  for (int r = 0; r < 4; ++r) {
    const float inv = 1.0f / accL[r];
    float* op = out + (size_t)(b * 2048 + q0 + wave * 16 + quad * 4 + r) * 1024 + h * 64;
#pragma unroll
    for (int j = 0; j < 4; ++j) op[j * 16 + lm] = acc_o[j][r] * inv;
  }
}

// ---------------------------------------------------------------------------
extern "C" void kernel_launch(void* const* d_in, const int* in_sizes, int n_in,
                              void* d_out, int out_size, void* d_ws, size_t ws_size,
                              hipStream_t stream) {
  const float* hidden = (const float*)d_in[0];
  const float* qk_w   = (const float*)d_in[1];
  const float* qk_b   = (const float*)d_in[2];
  const float* v_w    = (const float*)d_in[3];
  const float* v_b    = (const float*)d_in[4];
  const float* hash_a = (const float*)d_in[5];
  float* out = (float*)d_out;

  char* base = (char*)d_ws;
  size_t off = 0;
  auto take = [&](size_t bytes) -> char* {
    char* r = base + off;
    off += (bytes + 255) & ~(size_t)255;
    return r;
  };
  const size_t NH = 4194304;  // B*L*D
  const size_t NW = 1048576;  // D*D
  u16* hHi  = (u16*)take(NH * 2);
  u16* hLo  = (u16*)take(NH * 2);
  u16* wqHi = (u16*)take(NW * 2);
  u16* wqLo = (u16*)take(NW * 2);
  u16* wvHi = (u16*)take(NW * 2);
  u16* qkB  = (u16*)take(NH * 2);
  u16* vT   = (u16*)take(NH * 2);
  double* ca = (double*)take(16 * 1024 * 8);
  float* dq  = (float*)take(65536 * 4);
  float* n2A = (float*)take(65536 * 4);
  u8* hqA = (u8*)take(65536);
  u8* hkA = (u8*)take(65536);

  // prep: 24576 split blocks + 64 ca blocks
  hipLaunchKernelGGL(prep_kernel, dim3((NH + 2 * NW) / 256 + 64), dim3(256), 0, stream,
                     hidden, qk_w, v_w, hash_a, hHi, hLo, wqHi, wqLo, wvHi, ca);
  hipLaunchKernelGGL(d_kernel, dim3(1024), dim3(256), 0, stream, hidden, ca, dq);
  hipLaunchKernelGGL(gemm_fused, dim3(64, 8), dim3(256), 0, stream,
                     hHi, hLo, wqHi, wqLo, wvHi, qk_b, v_b, qkB, vT, n2A);
  hipLaunchKernelGGL(bits_kernel, dim3(32), dim3(256), 0, stream, n2A, dq, hash_a, hqA, hkA);
  hipLaunchKernelGGL(attn_kernel, dim3(32, 32), dim3(256), 0, stream, qkB, vT, hqA, hkA, out);
}

// Round 11
// 232.312 us; speedup vs baseline: 1.0434x; 1.0089x over previous
//
#include <hip/hip_runtime.h>

typedef unsigned short u16;
typedef unsigned char  u8;
typedef unsigned int   u32;

typedef short bf16x8 __attribute__((ext_vector_type(8)));
typedef float f32x4  __attribute__((ext_vector_type(4)));

#define DEV __device__ __forceinline__

#if __has_builtin(__builtin_amdgcn_exp2f)
#define EXP2(x) __builtin_amdgcn_exp2f(x)
#else
#define EXP2(x) exp2f(x)
#endif

DEV u16 f2bf(float x) {
  u32 u = __builtin_bit_cast(u32, x);
  u32 r = (u + 0x7fffu + ((u >> 16) & 1u)) >> 16;
  return (u16)r;
}
DEV float bf2f(u16 h) {
  u32 u = ((u32)h) << 16;
  return __builtin_bit_cast(float, u);
}
DEV f32x4 mfma16(bf16x8 a, bf16x8 b, f32x4 c) {
  return __builtin_amdgcn_mfma_f32_16x16x32_bf16(a, b, c, 0, 0, 0);
}

#define GLDS(gptr, lptr)                                                  \
  __builtin_amdgcn_global_load_lds(                                       \
      (const __attribute__((address_space(1))) void*)(gptr),              \
      (__attribute__((address_space(3))) void*)(lptr), 16, 0, 0)

// ---------------------------------------------------------------------------
// 1) merged preprocessing (raw inputs only):
//    blocks [0, 24576): split hidden->hi/lo, qk_w->hi/lo, v_w->hi
//    blocks [24576, 24640): ca[h][k] = sum_j qk_w[h*64+j][k]*a[j]  (fp64)
// ---------------------------------------------------------------------------
__global__ __launch_bounds__(256) void prep_kernel(
    const float* __restrict__ hid, const float* __restrict__ wq,
    const float* __restrict__ wv, const float* __restrict__ ha,
    u16* __restrict__ hHi, u16* __restrict__ hLo,
    u16* __restrict__ wqHi, u16* __restrict__ wqLo, u16* __restrict__ wvHi,
    double* __restrict__ ca) {
  const int NH = 4194304, NW = 1048576;
  int i = blockIdx.x * 256 + threadIdx.x;
  if (i < NH) {
    float v = hid[i];
    u16 t = f2bf(v);
    hHi[i] = t;
    hLo[i] = f2bf(v - bf2f(t));
  } else if (i < NH + NW) {
    int j = i - NH;
    float v = wq[j];
    u16 t = f2bf(v);
    wqHi[j] = t;
    wqLo[j] = f2bf(v - bf2f(t));
  } else if (i < NH + 2 * NW) {
    int j = i - NH - NW;
    wvHi[j] = f2bf(wv[j]);
  } else {
    int idx = i - NH - 2 * NW;  // 0 .. 16383
    int h = idx >> 10, k = idx & 1023;
    double s = 0.0;
#pragma unroll 8
    for (int j = 0; j < 64; ++j)
      s += (double)wq[(size_t)(h * 64 + j) * 1024 + k] * (double)ha[j];
    ca[idx] = s;
  }
}

// ---------------------------------------------------------------------------
// 3) d[bh][l] = sum_k hidden[row][k] * ca[h][k]   (fp64 acc; exact q-hash sign)
// ---------------------------------------------------------------------------
__global__ __launch_bounds__(256) void d_kernel(
    const float* __restrict__ hid, const double* __restrict__ ca, float* __restrict__ dq) {
  const int row  = blockIdx.x * 4 + (threadIdx.x >> 6);  // 0..4095
  const int lane = threadIdx.x & 63;
  const int b = row >> 11, l = row & 2047;
  double acc[16];
#pragma unroll
  for (int h = 0; h < 16; ++h) acc[h] = 0.0;
  const float* hp = hid + (size_t)row * 1024;
  for (int k = lane; k < 1024; k += 64) {
    const double hv = (double)hp[k];
#pragma unroll
    for (int h = 0; h < 16; ++h) acc[h] += hv * ca[h * 1024 + k];
  }
#pragma unroll
  for (int h = 0; h < 16; ++h) {
    double v = acc[h];
#pragma unroll
    for (int off = 32; off; off >>= 1) v += __shfl_xor(v, off, 64);
    if (lane == 0) dq[(size_t)(b * 16 + h) * 2048 + l] = (float)v;
  }
}

// ---------------------------------------------------------------------------
// 4) dual-output GEMM, grid (64,8), 2 blocks/CU, dbuf prefetch-after-barrier:
//    qk[tok][col] = hidden @ qk_w^T + qk_b  (3-term split)  -> qkB + n2A
//    vt[vcol][tok] = v_w @ hidden^T + v_b                  -> vT (stride 4096)
// ---------------------------------------------------------------------------
__global__ __launch_bounds__(256, 2) void gemm_fused(
    const u16* __restrict__ hHi, const u16* __restrict__ hLo,
    const u16* __restrict__ wqHi, const u16* __restrict__ wqLo,
    const u16* __restrict__ wvHi,
    const float* __restrict__ qk_b, const float* __restrict__ v_b,
    u16* __restrict__ qkB, u16* __restrict__ vT, float* __restrict__ n2A) {
  constexpr int K = 1024;
  // slots (u16): Ah 0, Al 2048, Bh 4096, Bl 8192, Wh 12288; buf stride 16384
  __shared__ u16 S[2][16384];
  const int tid = threadIdx.x, wave = tid >> 6, lane = tid & 63;
  const int quad = lane >> 4, lm = lane & 15;
  const int wr = wave >> 1, wc = wave & 1;
  const int m0 = blockIdx.x * 64, n0 = blockIdx.y * 128;
  const int ch = lane & 3, rA = lane >> 2;

  auto stage = [&](int kt, int buf) {
    const int k0 = kt * 32;
    const int rowA = wave * 16 + rA;
    GLDS(hHi + (size_t)(m0 + rowA) * K + k0 + ch * 8, &S[buf][0 + wave * 512]);
    GLDS(hLo + (size_t)(m0 + rowA) * K + k0 + ch * 8, &S[buf][2048 + wave * 512]);
#pragma unroll
    for (int it = 0; it < 2; ++it) {
      const int rb = wave * 2 + it;
      const int row = rb * 16 + rA;
      GLDS(wqHi + (size_t)(n0 + row) * K + k0 + ch * 8, &S[buf][4096 + rb * 512]);
      GLDS(wqLo + (size_t)(n0 + row) * K + k0 + ch * 8, &S[buf][8192 + rb * 512]);
      GLDS(wvHi + (size_t)(n0 + row) * K + k0 + ch * 8, &S[buf][12288 + rb * 512]);
    }
  };

  f32x4 aq[2][4], av[4][2];
#pragma unroll
  for (int i = 0; i < 2; ++i)
#pragma unroll
    for (int j = 0; j < 4; ++j) aq[i][j] = {0.f, 0.f, 0.f, 0.f};
#pragma unroll
  for (int i = 0; i < 4; ++i)
#pragma unroll
    for (int j = 0; j < 2; ++j) av[i][j] = {0.f, 0.f, 0.f, 0.f};

  stage(0, 0);
  __syncthreads();

  for (int kt = 0; kt < 32; ++kt) {
    const int cur = kt & 1;
    if (kt < 31) stage(kt + 1, cur ^ 1);

    bf16x8 a_h[2], a_l[2], b_h[4], b_l[4], w_h[4];
#pragma unroll
    for (int i = 0; i < 2; ++i) {
      a_h[i] = *(const bf16x8*)&S[cur][(wr * 32 + i * 16 + lm) * 32 + quad * 8];
      a_l[i] = *(const bf16x8*)&S[cur][2048 + (wr * 32 + i * 16 + lm) * 32 + quad * 8];
    }
#pragma unroll
    for (int j = 0; j < 4; ++j) {
      b_h[j] = *(const bf16x8*)&S[cur][4096 + (wc * 64 + j * 16 + lm) * 32 + quad * 8];
      b_l[j] = *(const bf16x8*)&S[cur][8192 + (wc * 64 + j * 16 + lm) * 32 + quad * 8];
      w_h[j] = *(const bf16x8*)&S[cur][12288 + (wc * 64 + j * 16 + lm) * 32 + quad * 8];
    }
#pragma unroll
    for (int i = 0; i < 2; ++i)
#pragma unroll
      for (int j = 0; j < 4; ++j) {
        aq[i][j] = mfma16(a_h[i], b_h[j], aq[i][j]);
        aq[i][j] = mfma16(a_h[i], b_l[j], aq[i][j]);
        aq[i][j] = mfma16(a_l[i], b_h[j], aq[i][j]);
      }
#pragma unroll
    for (int iv = 0; iv < 4; ++iv)
#pragma unroll
      for (int jv = 0; jv < 2; ++jv)
        av[iv][jv] = mfma16(w_h[iv], a_h[jv], av[iv][jv]);

    __syncthreads();
  }

  // qk epilogue + fused per-head n2 (wc-block == one head: cols n0+wc*64..+63)
  const int hidx = blockIdx.y * 2 + wc;
#pragma unroll
  for (int i = 0; i < 2; ++i) {
    float nn[4] = {0.f, 0.f, 0.f, 0.f};
#pragma unroll
    for (int j = 0; j < 4; ++j) {
      const int col = n0 + wc * 64 + j * 16 + lm;
      const float bv = qk_b[col];
#pragma unroll
      for (int r = 0; r < 4; ++r) {
        const int row = m0 + wr * 32 + i * 16 + quad * 4 + r;
        const float val = aq[i][j][r] + bv;
        qkB[(size_t)row * 1024 + col] = f2bf(val);
        nn[r] += val * val;
      }
    }
#pragma unroll
    for (int r = 0; r < 4; ++r)
#pragma unroll
      for (int off = 1; off < 16; off <<= 1) nn[r] += __shfl_xor(nn[r], off, 64);
    if (lm == 0) {
      const int row = m0 + wr * 32 + i * 16 + quad * 4;  // 4 consecutive rows
      const int b = row >> 11, l = row & 2047;
      *(float4*)&n2A[(size_t)(b * 16 + hidx) * 2048 + l] =
          make_float4(nn[0], nn[1], nn[2], nn[3]);
    }
  }
  // v epilogue: vT[vcol][token], token contiguous over lm
#pragma unroll
  for (int iv = 0; iv < 4; ++iv)
#pragma unroll
    for (int r = 0; r < 4; ++r) {
      const int vcol = n0 + wc * 64 + iv * 16 + quad * 4 + r;
      const float bv = v_b[vcol];
#pragma unroll
      for (int jv = 0; jv < 2; ++jv) {
        const int tok = m0 + wr * 32 + jv * 16 + lm;
        vT[(size_t)vcol * 4096 + tok] = f2bf(av[iv][jv][r] + bv);
      }
    }
}

// ---------------------------------------------------------------------------
// 5) hash bits per (b,h)
// ---------------------------------------------------------------------------
__global__ __launch_bounds__(256) void bits_kernel(
    const float* __restrict__ n2A, const float* __restrict__ dq,
    const float* __restrict__ ha, u8* __restrict__ hqA, u8* __restrict__ hkA) {
  const int bh = blockIdx.x;
  const int tid = threadIdx.x;
  const int wave = tid >> 6, lane = tid & 63;
  __shared__ float red[4];
  const float* n2p = n2A + (size_t)bh * 2048;
  float4 v0 = ((const float4*)n2p)[tid];
  float4 v1 = ((const float4*)n2p)[tid + 256];
  float lmax = fmaxf(fmaxf(fmaxf(v0.x, v0.y), fmaxf(v0.z, v0.w)),
                     fmaxf(fmaxf(v1.x, v1.y), fmaxf(v1.z, v1.w)));
#pragma unroll
  for (int off = 1; off < 64; off <<= 1) lmax = fmaxf(lmax, __shfl_xor(lmax, off, 64));
  if (lane == 0) red[wave] = lmax;
  __syncthreads();
  const float maxn2 = fmaxf(fmaxf(red[0], red[1]), fmaxf(red[2], red[3]));
  const float s = 0.75f / fmaxf(sqrtf(maxn2), 1e-12f);
  const float a64 = ha[64], a65 = ha[65];
#pragma unroll
  for (int it = 0; it < 8; ++it) {
    const int l = it * 256 + tid;
    const float dv = dq[(size_t)bh * 2048 + l];
    const float n2 = n2p[l];
    const float nk2 = s * s * n2;
    const float hkdot = s * dv + (0.5f - nk2) * a64 + (0.5f - nk2 * nk2) * a65;
    hqA[(size_t)bh * 2048 + l] = (dv >= 0.f) ? 1 : 0;
    hkA[(size_t)bh * 2048 + l] = (hkdot >= 0.f) ? 1 : 0;
  }
}

// ---------------------------------------------------------------------------
// 6) flash attention v4 (known-good): 64 q/block (16 q/wave), grid (32,32)
//    = 4 blocks/CU (LDS 40 KB), fixed-C softmax, dbuf GLDS staging w/ XOR
//    swizzle, 1 barrier/iter, l via MFMA-with-ones.
// ---------------------------------------------------------------------------
__global__ __launch_bounds__(256, 4) void attn_kernel(
    const u16* __restrict__ qkb, const u16* __restrict__ vT,
    const u8* __restrict__ hqA, const u8* __restrict__ hkA, float* __restrict__ out) {
  __shared__ u16 Ks[2][4096];   // [buf][key(64) x dim(64)], 16B-chunk XOR swizzle
  __shared__ u16 Vs[2][4096];   // [buf][dim(64) x key(64)], same swizzle
  __shared__ u16 Ps[4][1024];   // [wave][qrow(16) x key(64)], same swizzle

  const int qt = blockIdx.x;    // 0..31 (64 queries each)
  const int bh = blockIdx.y;    // 0..31
  const int b = bh >> 4, h = bh & 15;
  const int tid = threadIdx.x, wave = tid >> 6, lane = tid & 63;
  const int quad = lane >> 4, lm = lane & 15;
  const int lx = lm & 7;
  const int r8 = lane >> 3, ch = lane & 7;
  const int q0 = qt * 64;

  const u16* qbase = qkb + (size_t)b * 2048 * 1024 + h * 64;
  const u16* vtb = vT + (size_t)h * 64 * 4096 + b * 2048;  // row stride 4096
  const u8* hkp = hkA + (size_t)bh * 2048;

  // Q A-frags straight from global (raw; 1/sqrt(DH) folded into exp2 arg)
  bf16x8 aQ[2];
#pragma unroll
  for (int c = 0; c < 2; ++c)
    aQ[c] = *(const bf16x8*)(qbase +
        (size_t)(q0 + wave * 16 + lm) * 1024 + c * 32 + quad * 8);
  u8 hqb[4];
  {
    const u8* hqp = hqA + (size_t)bh * 2048 + q0 + wave * 16;
#pragma unroll
    for (int r = 0; r < 4; ++r) hqb[r] = hqp[quad * 4 + r];
  }

  const int srow = wave * 16;  // this wave's 16-row staging slab
  auto stage = [&](int kt, int buf) {
#pragma unroll
    for (int i = 0; i < 2; ++i) {
      const int row = srow + i * 8 + r8;  // key row for K / dim row for V
      const int sw = (ch ^ (row & 7)) * 8;
      GLDS(qbase + (size_t)(kt * 64 + row) * 1024 + sw, &Ks[buf][(srow + i * 8) * 64]);
      GLDS(vtb + (size_t)row * 4096 + kt * 64 + sw, &Vs[buf][(srow + i * 8) * 64]);
    }
  };

  stage(0, 0);

  f32x4 acc_o[4], accL;
  accL = {0.f, 0.f, 0.f, 0.f};
#pragma unroll
  for (int j = 0; j < 4; ++j) acc_o[j] = {0.f, 0.f, 0.f, 0.f};
  const bf16x8 ones = {0x3F80, 0x3F80, 0x3F80, 0x3F80, 0x3F80, 0x3F80, 0x3F80, 0x3F80};
  const float SCL = 0.18033688f;        // 0.125 * log2(e)
  const float M0 = -4.3280854f;         // -C*log2(e), C = 3
  const float M1 = -1.4430768e4f;       // -(1e4 + C)*log2(e)  -> exp2 underflows to 0

  __syncthreads();  // tile 0 staged (barrier drains vmcnt)

  for (int kt = 0; kt < 32; ++kt) {
    const int cur = kt & 1;
    if (kt < 31) stage(kt + 1, cur ^ 1);

    u8 hkv[4];
#pragma unroll
    for (int nb = 0; nb < 4; ++nb) hkv[nb] = hkp[kt * 64 + nb * 16 + lm];

    // S = Q K^T (raw dot products; scaling folded into exp)
    f32x4 cs[4];
#pragma unroll
    for (int nb = 0; nb < 4; ++nb) cs[nb] = {0.f, 0.f, 0.f, 0.f};
#pragma unroll
    for (int c = 0; c < 2; ++c)
#pragma unroll
      for (int nb = 0; nb < 4; ++nb) {
        bf16x8 bK = *(const bf16x8*)&Ks[cur][(nb * 16 + lm) * 64 + (((c * 4 + quad) ^ lx) * 8)];
        cs[nb] = mfma16(aQ[c], bK, cs[nb]);
      }

    // p = 2^(s*SCL + msel); write bf16 (truncation) into swizzled Ps
#pragma unroll
    for (int nb = 0; nb < 4; ++nb)
#pragma unroll
      for (int r = 0; r < 4; ++r) {
        const float msel = (hqb[r] == hkv[nb]) ? M0 : M1;
        const float p = EXP2(__builtin_fmaf(cs[nb][r], SCL, msel));
        const int prow = quad * 4 + r;
        const int pc = (nb * 2 + (lm >> 3)) ^ (prow & 7);
        union { float f; u16 hw[2]; } u;
        u.f = p;
        Ps[wave][prow * 64 + pc * 8 + lx] = u.hw[1];
      }

    // P frags (same-wave round trip; lgkm ordering, no barrier) + l via ones-MFMA
    bf16x8 aP[2];
#pragma unroll
    for (int c = 0; c < 2; ++c) {
      aP[c] = *(const bf16x8*)&Ps[wave][lm * 64 + (((c * 4 + quad) ^ lx) * 8)];
      accL = mfma16(aP[c], ones, accL);
    }
    // O += P V
#pragma unroll
    for (int c = 0; c < 2; ++c)
#pragma unroll
      for (int j = 0; j < 4; ++j) {
        bf16x8 bV = *(const bf16x8*)&Vs[cur][(j * 16 + lm) * 64 + (((c * 4 + quad) ^ lx) * 8)];
        acc_o[j] = mfma16(aP[c], bV, acc_o[j]);
      }

    __syncthreads();  // prev-tile reads done + next-tile staging drained
  }

#pragma unroll
  for (int r = 0; r < 4; ++r) {
    const float inv = 1.0f / accL[r];
    float* op = out + (size_t)(b * 2048 + q0 + wave * 16 + quad * 4 + r) * 1024 + h * 64;
#pragma unroll
    for (int j = 0; j < 4; ++j) op[j * 16 + lm] = acc_o[j][r] * inv;
  }
}

// ---------------------------------------------------------------------------
extern "C" void kernel_launch(void* const* d_in, const int* in_sizes, int n_in,
                              void* d_out, int out_size, void* d_ws, size_t ws_size,
                              hipStream_t stream) {
  const float* hidden = (const float*)d_in[0];
  const float* qk_w   = (const float*)d_in[1];
  const float* qk_b   = (const float*)d_in[2];
  const float* v_w    = (const float*)d_in[3];
  const float* v_b    = (const float*)d_in[4];
  const float* hash_a = (const float*)d_in[5];
  float* out = (float*)d_out;

  char* base = (char*)d_ws;
  size_t off = 0;
  auto take = [&](size_t bytes) -> char* {
    char* r = base + off;
    off += (bytes + 255) & ~(size_t)255;
    return r;
  };
  const size_t NH = 4194304;  // B*L*D
  const size_t NW = 1048576;  // D*D
  u16* hHi  = (u16*)take(NH * 2);
  u16* hLo  = (u16*)take(NH * 2);
  u16* wqHi = (u16*)take(NW * 2);
  u16* wqLo = (u16*)take(NW * 2);
  u16* wvHi = (u16*)take(NW * 2);
  u16* qkB  = (u16*)take(NH * 2);
  u16* vT   = (u16*)take(NH * 2);
  double* ca = (double*)take(16 * 1024 * 8);
  float* dq  = (float*)take(65536 * 4);
  float* n2A = (float*)take(65536 * 4);
  u8* hqA = (u8*)take(65536);
  u8* hkA = (u8*)take(65536);

  // prep: 24576 split blocks + 64 ca blocks
  hipLaunchKernelGGL(prep_kernel, dim3((NH + 2 * NW) / 256 + 64), dim3(256), 0, stream,
                     hidden, qk_w, v_w, hash_a, hHi, hLo, wqHi, wqLo, wvHi, ca);
  hipLaunchKernelGGL(d_kernel, dim3(1024), dim3(256), 0, stream, hidden, ca, dq);
  hipLaunchKernelGGL(gemm_fused, dim3(64, 8), dim3(256), 0, stream,
                     hHi, hLo, wqHi, wqLo, wvHi, qk_b, v_b, qkB, vT, n2A);
  hipLaunchKernelGGL(bits_kernel, dim3(32), dim3(256), 0, stream, n2A, dq, hash_a, hqA, hkA);
  hipLaunchKernelGGL(attn_kernel, dim3(32, 32), dim3(256), 0, stream, qkB, vT, hqA, hkA, out);
}